// Round 1
// baseline (634.477 us; speedup 1.0000x reference)
//
#include <hip/hip_runtime.h>
#include <math.h>

// LSTM fused: H=32, D=1, B=4096, T=1024.
// Lane j of a 32-lane group owns hidden unit j of one batch element.
// W_hh rows for the 4 gates live in VGPRs (128 regs). h exchanged via LDS
// broadcast reads. One block = 8 batch elements, 512 blocks total.

#define HH 32
#define TT 1024
#define BPB 8
#define NTHREADS 256

__device__ __forceinline__ float fast_sigmoid(float x) {
    // 1/(1+exp(-x)) via exp2
    float e = __builtin_amdgcn_exp2f(x * -1.4426950408889634f);
    return __builtin_amdgcn_rcpf(1.0f + e);
}

__device__ __forceinline__ float fast_tanh(float x) {
    // tanh(x) = 2/(1+exp(-2x)) - 1
    float e = __builtin_amdgcn_exp2f(x * -2.8853900817779268f);
    return fmaf(2.0f, __builtin_amdgcn_rcpf(1.0f + e), -1.0f);
}

__global__ __launch_bounds__(NTHREADS, 2)
void lstm_fused(const float* __restrict__ x,
                const float* __restrict__ W_ih,
                const float* __restrict__ W_hh,
                const float* __restrict__ b_ih,
                const float* __restrict__ b_hh,
                const float* __restrict__ fc_W,
                const float* __restrict__ fc_b,
                float* __restrict__ out)
{
    __shared__ float xs[BPB * TT];    // 32 KB: x rows for this block's 8 batch elems
    __shared__ float hs[BPB][HH];     // 1 KB: per-batch h vector, rebuilt each step

    const int tid = threadIdx.x;
    const int bl  = tid >> 5;         // local batch index 0..7
    const int j   = tid & 31;         // hidden unit index
    const int b0  = blockIdx.x * BPB;

    // ---- stage x into LDS (coalesced float4; 8 iters × 256 threads × 16 B) ----
    {
        const float4* xg  = (const float4*)(x + (size_t)b0 * TT);
        float4*       xs4 = (float4*)xs;
        #pragma unroll
        for (int it = 0; it < (BPB * TT / 4) / NTHREADS; ++it)
            xs4[it * NTHREADS + tid] = xg[it * NTHREADS + tid];
    }

    // ---- load recurrent weights into registers: 4 gate-rows of 32 ----
    // Gate order (PyTorch): i, f, g, o ; W_hh row m = gate*32 + j, length 32.
    float w[4][HH];
    #pragma unroll
    for (int g = 0; g < 4; ++g) {
        #pragma unroll
        for (int k4 = 0; k4 < HH / 4; ++k4) {
            float4 a = ((const float4*)(W_hh + (size_t)(g * HH + j) * HH))[k4];
            w[g][4 * k4 + 0] = a.x;
            w[g][4 * k4 + 1] = a.y;
            w[g][4 * k4 + 2] = a.z;
            w[g][4 * k4 + 3] = a.w;
        }
    }
    float wx[4], bb[4];
    #pragma unroll
    for (int g = 0; g < 4; ++g) {
        wx[g] = W_ih[g * HH + j];                       // D == 1
        bb[g] = b_ih[g * HH + j] + b_hh[g * HH + j];
    }

    float h = 0.0f, c = 0.0f;
    __syncthreads();   // xs visible to all waves

    const float* xrow = xs + bl * TT;

    #pragma unroll 1
    for (int t = 0; t < TT; ++t) {
        hs[bl][j] = h;
        __syncthreads();  // ordering fence (sharing is intra-wave; conservative)

        const float xv = xrow[t];
        float a0 = fmaf(xv, wx[0], bb[0]);
        float a1 = fmaf(xv, wx[1], bb[1]);
        float a2 = fmaf(xv, wx[2], bb[2]);
        float a3 = fmaf(xv, wx[3], bb[3]);

        const float4* hv = (const float4*)(&hs[bl][0]);  // broadcast reads
        #pragma unroll
        for (int k4 = 0; k4 < HH / 4; ++k4) {
            const float4 h4 = hv[k4];
            const float hx0 = h4.x, hx1 = h4.y, hx2 = h4.z, hx3 = h4.w;
            const int k = 4 * k4;
            a0 = fmaf(hx0, w[0][k + 0], a0);
            a1 = fmaf(hx0, w[1][k + 0], a1);
            a2 = fmaf(hx0, w[2][k + 0], a2);
            a3 = fmaf(hx0, w[3][k + 0], a3);
            a0 = fmaf(hx1, w[0][k + 1], a0);
            a1 = fmaf(hx1, w[1][k + 1], a1);
            a2 = fmaf(hx1, w[2][k + 1], a2);
            a3 = fmaf(hx1, w[3][k + 1], a3);
            a0 = fmaf(hx2, w[0][k + 2], a0);
            a1 = fmaf(hx2, w[1][k + 2], a1);
            a2 = fmaf(hx2, w[2][k + 2], a2);
            a3 = fmaf(hx2, w[3][k + 2], a3);
            a0 = fmaf(hx3, w[0][k + 3], a0);
            a1 = fmaf(hx3, w[1][k + 3], a1);
            a2 = fmaf(hx3, w[2][k + 3], a2);
            a3 = fmaf(hx3, w[3][k + 3], a3);
        }

        const float gi = fast_sigmoid(a0);
        const float gf = fast_sigmoid(a1);
        const float gg = fast_tanh(a2);
        const float go = fast_sigmoid(a3);
        c = fmaf(gf, c, gi * gg);
        h = go * fast_tanh(c);
    }

    // ---- epilogue: out[b] = fc_W . h + fc_b, reduce across the 32-lane group ----
    float p = h * fc_W[j];
    #pragma unroll
    for (int m = 16; m >= 1; m >>= 1)
        p += __shfl_xor(p, m, 32);
    if (j == 0)
        out[b0 + bl] = p + fc_b[0];
}

extern "C" void kernel_launch(void* const* d_in, const int* in_sizes, int n_in,
                              void* d_out, int out_size, void* d_ws, size_t ws_size,
                              hipStream_t stream) {
    const float* x    = (const float*)d_in[0];
    const float* W_ih = (const float*)d_in[1];
    const float* W_hh = (const float*)d_in[2];
    const float* b_ih = (const float*)d_in[3];
    const float* b_hh = (const float*)d_in[4];
    const float* fc_W = (const float*)d_in[5];
    const float* fc_b = (const float*)d_in[6];
    float* out = (float*)d_out;

    const int B = in_sizes[0] / TT;   // 4096 (D == 1)
    dim3 grid(B / BPB), block(NTHREADS);
    lstm_fused<<<grid, block, 0, stream>>>(x, W_ih, W_hh, b_ih, b_hh,
                                           fc_W, fc_b, out);
}

// Round 2
// 561.784 us; speedup vs baseline: 1.1294x; 1.1294x over previous
//
#include <hip/hip_runtime.h>
#include <math.h>

// LSTM fused: H=32, D=1, B=4096, T=1024.
// Lane j of a 32-lane group owns hidden unit j of one batch element.
// Recurrent weights held in VGPRs as fp16 pairs; h@W_hh^T via v_dot2_f32_f16
// (2 MACs/inst, fp32 accumulate). h exchanged per step through LDS as fp16.
// c-state, activations, epilogue all fp32.

#define HH 32
#define TT 1024
#define BPB 8
#define NTHREADS 256

typedef _Float16 half2_t __attribute__((ext_vector_type(2)));

__device__ __forceinline__ float dot2(half2_t a, half2_t b, float c) {
#if __has_builtin(__builtin_amdgcn_fdot2)
    return __builtin_amdgcn_fdot2(a, b, c, false);
#else
    return fmaf((float)a.x, (float)b.x, fmaf((float)a.y, (float)b.y, c));
#endif
}

__device__ __forceinline__ float fast_sigmoid(float x) {
    float e = __builtin_amdgcn_exp2f(x * -1.4426950408889634f);
    return __builtin_amdgcn_rcpf(1.0f + e);
}

__device__ __forceinline__ float fast_tanh(float x) {
    float e = __builtin_amdgcn_exp2f(x * -2.8853900817779268f);
    return fmaf(2.0f, __builtin_amdgcn_rcpf(1.0f + e), -1.0f);
}

__global__ __launch_bounds__(NTHREADS, 2)
void lstm_fused(const float* __restrict__ x,
                const float* __restrict__ W_ih,
                const float* __restrict__ W_hh,
                const float* __restrict__ b_ih,
                const float* __restrict__ b_hh,
                const float* __restrict__ fc_W,
                const float* __restrict__ fc_b,
                float* __restrict__ out)
{
    __shared__ float    xs[BPB * TT];      // 32 KB
    __shared__ _Float16 hs[BPB][HH];       // 512 B, h as fp16 per step

    const int tid = threadIdx.x;
    const int bl  = tid >> 5;              // local batch index 0..7
    const int j   = tid & 31;              // hidden unit index
    const int b0  = blockIdx.x * BPB;

    // ---- stage x into LDS (coalesced float4) ----
    {
        const float4* xg  = (const float4*)(x + (size_t)b0 * TT);
        float4*       xs4 = (float4*)xs;
        #pragma unroll
        for (int it = 0; it < (BPB * TT / 4) / NTHREADS; ++it)
            xs4[it * NTHREADS + tid] = xg[it * NTHREADS + tid];
    }

    // ---- recurrent weights -> fp16 pairs in VGPRs: 4 gates x 16 half2 = 64 regs ----
    half2_t w2[4][HH / 2];
    #pragma unroll
    for (int g = 0; g < 4; ++g) {
        const float* wrow = W_hh + (size_t)(g * HH + j) * HH;
        #pragma unroll
        for (int k2 = 0; k2 < HH / 2; ++k2) {
            half2_t p;
            p.x = (_Float16)wrow[2 * k2 + 0];   // RTN convert
            p.y = (_Float16)wrow[2 * k2 + 1];
            w2[g][k2] = p;
        }
    }
    float wx[4], bb[4];
    #pragma unroll
    for (int g = 0; g < 4; ++g) {
        wx[g] = W_ih[g * HH + j];                      // D == 1
        bb[g] = b_ih[g * HH + j] + b_hh[g * HH + j];
    }

    float h = 0.0f, c = 0.0f;
    __syncthreads();   // xs visible

    const float*  xrow   = xs + bl * TT;
    const float4* hsrow4 = (const float4*)(&hs[bl][0]);  // 64 B = 4 x b128

    #pragma unroll 1
    for (int t = 0; t < TT; ++t) {
        hs[bl][j] = (_Float16)h;          // ds_write_b16
        __syncthreads();                   // fence: writes visible before reads

        const float xv = xrow[t];
        float a0 = fmaf(xv, wx[0], bb[0]);
        float a1 = fmaf(xv, wx[1], bb[1]);
        float a2 = fmaf(xv, wx[2], bb[2]);
        float a3 = fmaf(xv, wx[3], bb[3]);

        // 4 broadcast ds_read_b128 -> 16 half2 of h (bitcast, zero repack cost)
        #pragma unroll
        for (int i = 0; i < 4; ++i) {
            const float4 q = hsrow4[i];
            const half2_t p0 = __builtin_bit_cast(half2_t, q.x);
            const half2_t p1 = __builtin_bit_cast(half2_t, q.y);
            const half2_t p2 = __builtin_bit_cast(half2_t, q.z);
            const half2_t p3 = __builtin_bit_cast(half2_t, q.w);
            const int k2 = 4 * i;
            a0 = dot2(w2[0][k2 + 0], p0, a0);
            a1 = dot2(w2[1][k2 + 0], p0, a1);
            a2 = dot2(w2[2][k2 + 0], p0, a2);
            a3 = dot2(w2[3][k2 + 0], p0, a3);
            a0 = dot2(w2[0][k2 + 1], p1, a0);
            a1 = dot2(w2[1][k2 + 1], p1, a1);
            a2 = dot2(w2[2][k2 + 1], p1, a2);
            a3 = dot2(w2[3][k2 + 1], p1, a3);
            a0 = dot2(w2[0][k2 + 2], p2, a0);
            a1 = dot2(w2[1][k2 + 2], p2, a1);
            a2 = dot2(w2[2][k2 + 2], p2, a2);
            a3 = dot2(w2[3][k2 + 2], p2, a3);
            a0 = dot2(w2[0][k2 + 3], p3, a0);
            a1 = dot2(w2[1][k2 + 3], p3, a1);
            a2 = dot2(w2[2][k2 + 3], p3, a2);
            a3 = dot2(w2[3][k2 + 3], p3, a3);
        }

        const float gi = fast_sigmoid(a0);
        const float gf = fast_sigmoid(a1);
        const float gg = fast_tanh(a2);
        const float go = fast_sigmoid(a3);
        c = fmaf(gf, c, gi * gg);
        h = go * fast_tanh(c);
        __syncthreads();   // reads done before next step's write
    }

    // ---- epilogue: out[b] = fc_W . h + fc_b (fp32), reduce across 32 lanes ----
    float p = h * fc_W[j];
    #pragma unroll
    for (int m = 16; m >= 1; m >>= 1)
        p += __shfl_xor(p, m, 32);
    if (j == 0)
        out[b0 + bl] = p + fc_b[0];
}

extern "C" void kernel_launch(void* const* d_in, const int* in_sizes, int n_in,
                              void* d_out, int out_size, void* d_ws, size_t ws_size,
                              hipStream_t stream) {
    const float* x    = (const float*)d_in[0];
    const float* W_ih = (const float*)d_in[1];
    const float* W_hh = (const float*)d_in[2];
    const float* b_ih = (const float*)d_in[3];
    const float* b_hh = (const float*)d_in[4];
    const float* fc_W = (const float*)d_in[5];
    const float* fc_b = (const float*)d_in[6];
    float* out = (float*)d_out;

    const int B = in_sizes[0] / TT;   // 4096 (D == 1)
    dim3 grid(B / BPB), block(NTHREADS);
    lstm_fused<<<grid, block, 0, stream>>>(x, W_ih, W_hh, b_ih, b_hh,
                                           fc_W, fc_b, out);
}

// Round 3
// 493.067 us; speedup vs baseline: 1.2868x; 1.1394x over previous
//
#include <hip/hip_runtime.h>
#include <math.h>

// LSTM fused: H=32, D=1, B=4096, T=1024.
// Lane j of a 32-lane group owns hidden unit j of one batch element (2 groups
// per wave). Recurrent weights in VGPRs as fp16 pairs, consumed by
// v_dot2_f32_f16. h exchanged via wave-private LDS (no barriers in hot loop:
// all sharing is intra-wave, ordered by lgkmcnt).
// amdgpu_waves_per_eu(2,2) pins the regalloc budget to 256 VGPRs so the
// 64-reg weight array is NOT demoted to AGPRs (round-2 lesson: default
// heuristic targeted 7 waves/EU -> 72 VGPRs -> v_accvgpr_read per dot).

#define HH 32
#define TT 1024
#define BPB 8
#define NTHREADS 256

typedef _Float16 half2_t __attribute__((ext_vector_type(2)));

__device__ __forceinline__ float dot2(half2_t a, half2_t b, float c) {
    return __builtin_amdgcn_fdot2(a, b, c, false);
}

__device__ __forceinline__ float fast_sigmoid(float x) {
    float e = __builtin_amdgcn_exp2f(x * -1.4426950408889634f);
    return __builtin_amdgcn_rcpf(1.0f + e);
}

__device__ __forceinline__ float fast_tanh(float x) {
    float e = __builtin_amdgcn_exp2f(x * -2.8853900817779268f);
    return fmaf(2.0f, __builtin_amdgcn_rcpf(1.0f + e), -1.0f);
}

__global__ __attribute__((amdgpu_flat_work_group_size(NTHREADS, NTHREADS),
                          amdgpu_waves_per_eu(2, 2)))
void lstm_fused(const float* __restrict__ x,
                const float* __restrict__ W_ih,
                const float* __restrict__ W_hh,
                const float* __restrict__ b_ih,
                const float* __restrict__ b_hh,
                const float* __restrict__ fc_W,
                const float* __restrict__ fc_b,
                float* __restrict__ out)
{
    __shared__ float    xs[BPB * TT];      // 32 KB
    __shared__ _Float16 hs[BPB][HH];       // 512 B

    const int tid = threadIdx.x;
    const int bl  = tid >> 5;              // local batch index 0..7
    const int j   = tid & 31;              // hidden unit index
    const int b0  = blockIdx.x * BPB;

    // ---- stage x into LDS (coalesced float4) ----
    {
        const float4* xg  = (const float4*)(x + (size_t)b0 * TT);
        float4*       xs4 = (float4*)xs;
        #pragma unroll
        for (int it = 0; it < (BPB * TT / 4) / NTHREADS; ++it)
            xs4[it * NTHREADS + tid] = xg[it * NTHREADS + tid];
    }

    // ---- recurrent weights -> fp16 pairs in VGPRs: 4 gates x 16 half2 ----
    half2_t w2[4][HH / 2];
    #pragma unroll
    for (int g = 0; g < 4; ++g) {
        const float* wrow = W_hh + (size_t)(g * HH + j) * HH;
        #pragma unroll
        for (int k2 = 0; k2 < HH / 2; ++k2) {
            half2_t p;
            p.x = (_Float16)wrow[2 * k2 + 0];
            p.y = (_Float16)wrow[2 * k2 + 1];
            w2[g][k2] = p;
        }
    }
    float wx[4], bb[4];
    #pragma unroll
    for (int g = 0; g < 4; ++g) {
        wx[g] = W_ih[g * HH + j];                      // D == 1
        bb[g] = b_ih[g * HH + j] + b_hh[g * HH + j];
    }

    float h = 0.0f, c = 0.0f;
    __syncthreads();   // xs visible (only barrier in the kernel)

    const float*  xrow   = xs + bl * TT;
    const float4* hsrow4 = (const float4*)(&hs[bl][0]);

    #pragma unroll 1
    for (int t = 0; t < TT; ++t) {
        // Intra-wave exchange: each group (32 lanes) lives in one wave, so
        // ds_write -> ds_read is ordered by lgkmcnt; no __syncthreads needed.
        hs[bl][j] = (_Float16)h;

        const float xv = xrow[t];
        float a0 = fmaf(xv, wx[0], bb[0]);
        float a1 = fmaf(xv, wx[1], bb[1]);
        float a2 = fmaf(xv, wx[2], bb[2]);
        float a3 = fmaf(xv, wx[3], bb[3]);

        #pragma unroll
        for (int i = 0; i < 4; ++i) {
            const float4 q = hsrow4[i];                // broadcast ds_read_b128
            const half2_t p0 = __builtin_bit_cast(half2_t, q.x);
            const half2_t p1 = __builtin_bit_cast(half2_t, q.y);
            const half2_t p2 = __builtin_bit_cast(half2_t, q.z);
            const half2_t p3 = __builtin_bit_cast(half2_t, q.w);
            const int k2 = 4 * i;
            a0 = dot2(w2[0][k2 + 0], p0, a0);
            a1 = dot2(w2[1][k2 + 0], p0, a1);
            a2 = dot2(w2[2][k2 + 0], p0, a2);
            a3 = dot2(w2[3][k2 + 0], p0, a3);
            a0 = dot2(w2[0][k2 + 1], p1, a0);
            a1 = dot2(w2[1][k2 + 1], p1, a1);
            a2 = dot2(w2[2][k2 + 1], p1, a2);
            a3 = dot2(w2[3][k2 + 1], p1, a3);
            a0 = dot2(w2[0][k2 + 2], p2, a0);
            a1 = dot2(w2[1][k2 + 2], p2, a1);
            a2 = dot2(w2[2][k2 + 2], p2, a2);
            a3 = dot2(w2[3][k2 + 2], p2, a3);
            a0 = dot2(w2[0][k2 + 3], p3, a0);
            a1 = dot2(w2[1][k2 + 3], p3, a1);
            a2 = dot2(w2[2][k2 + 3], p3, a2);
            a3 = dot2(w2[3][k2 + 3], p3, a3);
        }

        const float gi = fast_sigmoid(a0);
        const float gf = fast_sigmoid(a1);
        const float gg = fast_tanh(a2);
        const float go = fast_sigmoid(a3);
        c = fmaf(gf, c, gi * gg);
        h = go * fast_tanh(c);
    }

    // ---- epilogue: out[b] = fc_W . h + fc_b (fp32), reduce across 32 lanes ----
    float p = h * fc_W[j];
    #pragma unroll
    for (int m = 16; m >= 1; m >>= 1)
        p += __shfl_xor(p, m, 32);
    if (j == 0)
        out[b0 + bl] = p + fc_b[0];
}

extern "C" void kernel_launch(void* const* d_in, const int* in_sizes, int n_in,
                              void* d_out, int out_size, void* d_ws, size_t ws_size,
                              hipStream_t stream) {
    const float* x    = (const float*)d_in[0];
    const float* W_ih = (const float*)d_in[1];
    const float* W_hh = (const float*)d_in[2];
    const float* b_ih = (const float*)d_in[3];
    const float* b_hh = (const float*)d_in[4];
    const float* fc_W = (const float*)d_in[5];
    const float* fc_b = (const float*)d_in[6];
    float* out = (float*)d_out;

    const int B = in_sizes[0] / TT;   // 4096 (D == 1)
    dim3 grid(B / BPB), block(NTHREADS);
    lstm_fused<<<grid, block, 0, stream>>>(x, W_ih, W_hh, b_ih, b_hh,
                                           fc_W, fc_b, out);
}